// Round 1
// baseline (189.255 us; speedup 1.0000x reference)
//
#include <hip/hip_runtime.h>
#include <math.h>

typedef float        f32x4 __attribute__((ext_vector_type(4)));
typedef unsigned int u32x4 __attribute__((ext_vector_type(4)));

static constexpr int DIM    = 33;
static constexpr int LUT_N  = DIM * DIM * DIM;          // 35937
static constexpr int HW     = 1024 * 1024;
static constexpr int BATCH  = 8;
static constexpr long NPIX  = (long)BATCH * HW;         // 8388608
static constexpr long NTASK = NPIX / 4;                 // for fallback kernel

static constexpr size_t QT_BYTES  = (size_t)LUT_N * 4;  // 143,748 B
static constexpr size_t MM_OFF    = 143872;             // 128B-aligned, > QT_BYTES
static constexpr size_t LDS_BYTES = QT_BYTES;           // 140.4 KiB of LDS

// apply geometry: 256 blocks x 1024 threads. Each thread owns pixel quad
// hw = 4*gtid (2^18 threads * 4 px = HW exactly) and iterates the 8 batch
// images; the per-image address stride is the compile-time constant 3*HW.
static constexpr int ABLK = 256;
static constexpr int ATHR = 1024;

// ---------------------------------------------------------------------------
// helpers
// ---------------------------------------------------------------------------
__device__ __forceinline__ f32x4 ntl4(const float* p) {
    return __builtin_nontemporal_load((const f32x4*)p);
}
__device__ __forceinline__ void nts4(float* p, f32x4 v) {
    __builtin_nontemporal_store(v, (f32x4*)p);
}
__device__ __forceinline__ float d_r(unsigned n) { return (float)(n & 1023u); }
__device__ __forceinline__ float d_g(unsigned n) { return (float)((n >> 10) & 1023u); }
__device__ __forceinline__ float d_b(unsigned n) { return (float)(n >> 20); }

// ---------------------------------------------------------------------------
// Pass 1: min/max of the LUT (single block, vectorized float4 + unroll so the
// single-CU read is latency-hidden; ~431 KB total).
// ---------------------------------------------------------------------------
__global__ __launch_bounds__(1024) void lut_minmax(
    const float* __restrict__ lut, float* __restrict__ mm) {
    __shared__ float smin[1024], smax[1024];
    int t = threadIdx.x;
    float vmin = 1e30f, vmax = -1e30f;
    const f32x4* l4 = (const f32x4*)lut;
    const int NV = (3 * LUT_N) / 4;  // 26952 full float4s (covers 107808 elems)
#pragma unroll 4
    for (int i = t; i < NV; i += 1024) {
        f32x4 v = l4[i];
        vmin = fminf(vmin, fminf(fminf(v[0], v[1]), fminf(v[2], v[3])));
        vmax = fmaxf(vmax, fmaxf(fmaxf(v[0], v[1]), fmaxf(v[2], v[3])));
    }
    if (t < 3) {  // tail: elements 107808..107810
        float v = lut[NV * 4 + t];
        vmin = fminf(vmin, v);
        vmax = fmaxf(vmax, v);
    }
    smin[t] = vmin; smax[t] = vmax;
    __syncthreads();
    for (int s = 512; s > 0; s >>= 1) {
        if (t < s) {
            smin[t] = fminf(smin[t], smin[t + s]);
            smax[t] = fmaxf(smax[t], smax[t + s]);
        }
        __syncthreads();
    }
    if (t == 0) { mm[0] = smin[0]; mm[1] = smax[0]; }
}

// ---------------------------------------------------------------------------
// Pass 2: pack each LUT node as u10 r | g<<10 | b<<20 in one u32.
// ---------------------------------------------------------------------------
__global__ __launch_bounds__(256) void repack_u10(
    const float* __restrict__ lut, unsigned* __restrict__ qt,
    const float* __restrict__ mm) {
    int i = blockIdx.x * 256 + threadIdx.x;
    if (i >= LUT_N) return;
    float mn = mm[0], mx = mm[1];
    float range = mx - mn;
    if (range < 1e-20f) range = 1e-20f;
    float scale = 1023.0f / range;
    unsigned qr = (unsigned)__float2int_rn((lut[i] - mn) * scale);
    unsigned qg = (unsigned)__float2int_rn((lut[LUT_N + i] - mn) * scale);
    unsigned qb = (unsigned)__float2int_rn((lut[2 * LUT_N + i] - mn) * scale);
    qt[i] = qr | (qg << 10) | (qb << 20);
}

// ---------------------------------------------------------------------------
// Pass 3: apply with the whole u10 LUT in LDS (140.4 KiB -> 1 block/CU,
// 16 waves). Occupancy is LDS-capped, so the win must come from ILP:
//  - batch-image loop with constant 3*HW stride (b-index == iteration)
//  - software pipeline: next image's float4 loads issue before current compute
//  - truncation-cvt instead of floorf (exact after clamp), weight-form interp
//  - nontemporal float4 streaming for x/out (read/written exactly once)
// ---------------------------------------------------------------------------
__global__ __launch_bounds__(1024) void lut_apply_lds(
    const float* __restrict__ x, const unsigned* __restrict__ qt,
    const float* __restrict__ mm, float* __restrict__ out) {
    extern __shared__ unsigned sl[];
    // stage packed LUT into LDS, vectorized (8984 u32x4 + 1 tail dword)
    {
        const u32x4* q4 = (const u32x4*)qt;
        u32x4* s4 = (u32x4*)sl;
#pragma unroll
        for (int k = 0; k < 9; ++k) {
            int i = threadIdx.x + k * 1024;
            if (i < LUT_N / 4) s4[i] = q4[i];
        }
        if (threadIdx.x == 0) sl[LUT_N - 1] = qt[LUT_N - 1];
    }
    float mn = mm[0];
    float range = mm[1] - mn;
    if (range < 1e-20f) range = 1e-20f;
    float inv = range * (1.0f / 1023.0f);
    __syncthreads();

    const int gtid = blockIdx.x * ATHR + threadIdx.x;   // [0, 2^18)
    const size_t hw4 = (size_t)gtid * 4;                // [0, HW)
    const float* xp = x + hw4;
    float*       op = out + hw4;

    // prologue: image 0
    f32x4 rc = ntl4(xp);
    f32x4 gc = ntl4(xp + HW);
    f32x4 bc = ntl4(xp + 2 * (size_t)HW);

    for (int it = 0; it < BATCH; ++it) {
        // issue next image's loads early (hidden under this image's compute)
        f32x4 rn = {}, gn = {}, bn = {};
        if (it != BATCH - 1) {
            const float* xn = xp + (size_t)(it + 1) * (3 * (size_t)HW);
            rn = ntl4(xn);
            gn = ntl4(xn + HW);
            bn = ntl4(xn + 2 * (size_t)HW);
        }

        // phase 1: indices + all 32 LDS gathers for the 4 pixels
        unsigned n[4][8];
        float fr[4], fg[4], fb[4];
#pragma unroll
        for (int i = 0; i < 4; ++i) {
            const float scale = (float)(DIM - 1);
            float rs = rc[i] * scale, gs = gc[i] * scale, bs = bc[i] * scale;
            int ir = (int)rs; ir = ir < 0 ? 0 : (ir > DIM - 2 ? DIM - 2 : ir);
            int ig = (int)gs; ig = ig < 0 ? 0 : (ig > DIM - 2 ? DIM - 2 : ig);
            int ib = (int)bs; ib = ib < 0 ? 0 : (ib > DIM - 2 ? DIM - 2 : ib);
            fr[i] = rs - (float)ir;
            fg[i] = gs - (float)ig;
            fb[i] = bs - (float)ib;
            int s = ib * (DIM * DIM) + ig * DIM + ir;
            n[i][0] = sl[s];                     n[i][1] = sl[s + 1];
            n[i][2] = sl[s + DIM];               n[i][3] = sl[s + DIM + 1];
            n[i][4] = sl[s + DIM * DIM];         n[i][5] = sl[s + DIM * DIM + 1];
            n[i][6] = sl[s + DIM * DIM + DIM];   n[i][7] = sl[s + DIM * DIM + DIM + 1];
        }

        // phase 2: decode + weighted sum (weights shared across 3 channels)
        f32x4 orv, ogv, obv;
#pragma unroll
        for (int i = 0; i < 4; ++i) {
            float frc = 1.0f - fr[i], fgc = 1.0f - fg[i], fbc = 1.0f - fb[i];
            float w00 = fbc * fgc, w01 = fbc * fg[i];
            float w10 = fb[i] * fgc, w11 = fb[i] * fg[i];
            float u0 = w00 * frc, u1 = w00 * fr[i];
            float u2 = w01 * frc, u3 = w01 * fr[i];
            float u4 = w10 * frc, u5 = w10 * fr[i];
            float u6 = w11 * frc, u7 = w11 * fr[i];

            float qr = u0 * d_r(n[i][0]);
            qr = fmaf(u1, d_r(n[i][1]), qr);
            qr = fmaf(u2, d_r(n[i][2]), qr);
            qr = fmaf(u3, d_r(n[i][3]), qr);
            qr = fmaf(u4, d_r(n[i][4]), qr);
            qr = fmaf(u5, d_r(n[i][5]), qr);
            qr = fmaf(u6, d_r(n[i][6]), qr);
            qr = fmaf(u7, d_r(n[i][7]), qr);

            float qg = u0 * d_g(n[i][0]);
            qg = fmaf(u1, d_g(n[i][1]), qg);
            qg = fmaf(u2, d_g(n[i][2]), qg);
            qg = fmaf(u3, d_g(n[i][3]), qg);
            qg = fmaf(u4, d_g(n[i][4]), qg);
            qg = fmaf(u5, d_g(n[i][5]), qg);
            qg = fmaf(u6, d_g(n[i][6]), qg);
            qg = fmaf(u7, d_g(n[i][7]), qg);

            float qb = u0 * d_b(n[i][0]);
            qb = fmaf(u1, d_b(n[i][1]), qb);
            qb = fmaf(u2, d_b(n[i][2]), qb);
            qb = fmaf(u3, d_b(n[i][3]), qb);
            qb = fmaf(u4, d_b(n[i][4]), qb);
            qb = fmaf(u5, d_b(n[i][5]), qb);
            qb = fmaf(u6, d_b(n[i][6]), qb);
            qb = fmaf(u7, d_b(n[i][7]), qb);

            orv[i] = fmaf(qr, inv, mn);
            ogv[i] = fmaf(qg, inv, mn);
            obv[i] = fmaf(qb, inv, mn);
        }

        float* o = op + (size_t)it * (3 * (size_t)HW);
        nts4(o, orv);
        nts4(o + HW, ogv);
        nts4(o + 2 * (size_t)HW, obv);

        rc = rn; gc = gn; bc = bn;
    }
}

// ---------------------------------------------------------------------------
// Fallback: direct SoA gathers, exact fp32 (no workspace needed).
// ---------------------------------------------------------------------------
__global__ __launch_bounds__(256) void lut_apply_soa(
    const float* __restrict__ x, const float* __restrict__ lut,
    float* __restrict__ out) {
    long t = (long)blockIdx.x * 256 + threadIdx.x;
    long p = t * 4;
    int  b  = (int)(p >> 20);
    int  hw = (int)(p & (HW - 1));
    size_t base = (size_t)b * (3 * (size_t)HW) + (size_t)hw;

    float4 rv = *(const float4*)(x + base);
    float4 gv = *(const float4*)(x + base + (size_t)HW);
    float4 bv = *(const float4*)(x + base + 2 * (size_t)HW);

    float rr[4] = {rv.x, rv.y, rv.z, rv.w};
    float gg[4] = {gv.x, gv.y, gv.z, gv.w};
    float bb[4] = {bv.x, bv.y, bv.z, bv.w};
    float orr[4], org[4], orb[4];

#pragma unroll
    for (int i = 0; i < 4; ++i) {
        const float scale = (float)(DIM - 1);
        float rs = rr[i] * scale, gs = gg[i] * scale, bs = bb[i] * scale;
        int ir = (int)floorf(rs); ir = ir < 0 ? 0 : (ir > DIM - 2 ? DIM - 2 : ir);
        int ig = (int)floorf(gs); ig = ig < 0 ? 0 : (ig > DIM - 2 ? DIM - 2 : ig);
        int ib = (int)floorf(bs); ib = ib < 0 ? 0 : (ib > DIM - 2 ? DIM - 2 : ib);
        float fr = rs - (float)ir, fg = gs - (float)ig, fb = bs - (float)ib;
        int base_i = (ib * DIM + ig) * DIM + ir;
        float acc[3] = {0.f, 0.f, 0.f};
#pragma unroll
        for (int db = 0; db < 2; ++db) {
            float wb = db ? fb : 1.f - fb;
#pragma unroll
            for (int dg = 0; dg < 2; ++dg) {
                float wg = dg ? fg : 1.f - fg;
#pragma unroll
                for (int dr = 0; dr < 2; ++dr) {
                    float wr = dr ? fr : 1.f - fr;
                    int idx = base_i + (db * DIM + dg) * DIM + dr;
                    float w = wb * wg * wr;
                    acc[0] = fmaf(w, lut[idx], acc[0]);
                    acc[1] = fmaf(w, lut[LUT_N + idx], acc[1]);
                    acc[2] = fmaf(w, lut[2 * LUT_N + idx], acc[2]);
                }
            }
        }
        orr[i] = acc[0]; org[i] = acc[1]; orb[i] = acc[2];
    }

    *(float4*)(out + base)                  = make_float4(orr[0], orr[1], orr[2], orr[3]);
    *(float4*)(out + base + (size_t)HW)     = make_float4(org[0], org[1], org[2], org[3]);
    *(float4*)(out + base + 2 * (size_t)HW) = make_float4(orb[0], orb[1], orb[2], orb[3]);
}

extern "C" void kernel_launch(void* const* d_in, const int* in_sizes, int n_in,
                              void* d_out, int out_size, void* d_ws, size_t ws_size,
                              hipStream_t stream) {
    const float* lut = (const float*)d_in[0];
    const float* x   = (const float*)d_in[1];
    if (n_in >= 2 && in_sizes[0] > in_sizes[1]) {  // defensive: order swapped
        lut = (const float*)d_in[1];
        x   = (const float*)d_in[0];
    }
    float* out = (float*)d_out;

    const size_t need = MM_OFF + 2 * sizeof(float);
    if (ws_size >= need) {
        unsigned* qt = (unsigned*)d_ws;
        float*    mm = (float*)((char*)d_ws + MM_OFF);
        // Allow >64KB dynamic LDS (gfx950 has 160 KiB). Host-side attr set,
        // idempotent, graph-capture safe.
        (void)hipFuncSetAttribute((const void*)lut_apply_lds,
                                  hipFuncAttributeMaxDynamicSharedMemorySize,
                                  (int)LDS_BYTES);
        lut_minmax<<<1, 1024, 0, stream>>>(lut, mm);
        repack_u10<<<(LUT_N + 255) / 256, 256, 0, stream>>>(lut, qt, mm);
        lut_apply_lds<<<ABLK, ATHR, LDS_BYTES, stream>>>(x, qt, mm, out);
    } else {
        lut_apply_soa<<<(int)(NTASK / 256), 256, 0, stream>>>(x, lut, out);
    }
}

// Round 2
// 188.618 us; speedup vs baseline: 1.0034x; 1.0034x over previous
//
#include <hip/hip_runtime.h>
#include <math.h>

typedef float        f32x4 __attribute__((ext_vector_type(4)));
typedef unsigned int u32x4 __attribute__((ext_vector_type(4)));

static constexpr int DIM    = 33;
static constexpr int LUT_N  = DIM * DIM * DIM;          // 35937
static constexpr int HW     = 1024 * 1024;
static constexpr int BATCH  = 8;
static constexpr long NPIX  = (long)BATCH * HW;         // 8388608
static constexpr long NTASK = NPIX / 4;                 // fallback only

static constexpr size_t QT_BYTES  = (size_t)LUT_N * 4;  // 143,748 B
static constexpr size_t LDS_BYTES = 143872;             // 128B-rounded, < 160 KiB

// apply geometry: 256 blocks x 1024 threads == HW/4 threads exactly.
// Each thread owns pixel quad hw = 4*gtid and iterates the 8 batch images;
// the per-image address stride is the compile-time constant 3*HW.
static constexpr int ABLK = 256;
static constexpr int ATHR = 1024;

// ---------------------------------------------------------------------------
// helpers
// ---------------------------------------------------------------------------
__device__ __forceinline__ f32x4 ntl4(const float* p) {
    return __builtin_nontemporal_load((const f32x4*)p);
}
__device__ __forceinline__ void nts4(float* p, f32x4 v) {
    __builtin_nontemporal_store(v, (f32x4*)p);
}
__device__ __forceinline__ float d_r(unsigned n) { return (float)(n & 1023u); }
__device__ __forceinline__ float d_g(unsigned n) { return (float)((n >> 10) & 1023u); }
__device__ __forceinline__ float d_b(unsigned n) { return (float)(n >> 20); }

// ---------------------------------------------------------------------------
// Fused single kernel:
//   stage A: per-block LUT min/max (431 KB, L2-resident; order-independent so
//            per-block recomputation is exact)
//   stage B: quantize LUT nodes to u10 r|g<<10|b<<20 directly into LDS
//   stage C: streaming trilinear apply (float4 nontemporal IO, batch-image
//            loop with constant 3*HW stride, next-image loads prefetched)
// One launch, no workspace, no inter-kernel serialization.
// ---------------------------------------------------------------------------
__global__ __launch_bounds__(1024) void lut_fused(
    const float* __restrict__ x, const float* __restrict__ lut,
    float* __restrict__ out) {
    extern __shared__ unsigned sl[];
    const int t = threadIdx.x;

    // ---- stage A: block-wide min/max over all 3*LUT_N floats ----
    float vmin = 1e30f, vmax = -1e30f;
    {
        const f32x4* l4 = (const f32x4*)lut;        // base is 16B-aligned
        const int NV = (3 * LUT_N) / 4;             // 26952 full float4s
#pragma unroll 4
        for (int i = t; i < NV; i += 1024) {
            f32x4 v = l4[i];
            vmin = fminf(vmin, fminf(fminf(v[0], v[1]), fminf(v[2], v[3])));
            vmax = fmaxf(vmax, fmaxf(fmaxf(v[0], v[1]), fmaxf(v[2], v[3])));
        }
        if (t < 3) {                                 // tail elems 107808..107810
            float v = lut[NV * 4 + t];
            vmin = fminf(vmin, v);
            vmax = fmaxf(vmax, v);
        }
    }
    // wave reduce (64 lanes), then cross-wave via 32 floats of LDS
#pragma unroll
    for (int off = 32; off > 0; off >>= 1) {
        vmin = fminf(vmin, __shfl_down(vmin, off));
        vmax = fmaxf(vmax, __shfl_down(vmax, off));
    }
    float* sf = (float*)sl;
    if ((t & 63) == 0) { sf[t >> 6] = vmin; sf[16 + (t >> 6)] = vmax; }
    __syncthreads();
    float mn = sf[0], mx = sf[16];
#pragma unroll
    for (int k = 1; k < 16; ++k) {
        mn = fminf(mn, sf[k]);
        mx = fmaxf(mx, sf[16 + k]);
    }
    __syncthreads();  // everyone holds mn/mx in registers; sl may be reused

    float range = mx - mn;
    if (range < 1e-20f) range = 1e-20f;
    const float qscale = 1023.0f / range;
    const float inv    = range * (1.0f / 1023.0f);

    // ---- stage B: quantize LUT into LDS (scalar loads: lut+LUT_N is only
    // 4B-aligned, and these reads are L2-hot anyway) ----
    for (int i = t; i < LUT_N; i += 1024) {
        float r = lut[i], g = lut[LUT_N + i], b = lut[2 * LUT_N + i];
        unsigned qr = (unsigned)__float2int_rn((r - mn) * qscale);
        unsigned qg = (unsigned)__float2int_rn((g - mn) * qscale);
        unsigned qb = (unsigned)__float2int_rn((b - mn) * qscale);
        sl[i] = qr | (qg << 10) | (qb << 20);
    }
    __syncthreads();

    // ---- stage C: apply ----
    const int gtid = blockIdx.x * ATHR + t;          // [0, 2^18)
    const size_t hw4 = (size_t)gtid * 4;             // [0, HW)
    const float* xp = x + hw4;
    float*       op = out + hw4;

    // prologue: image 0
    f32x4 rc = ntl4(xp);
    f32x4 gc = ntl4(xp + HW);
    f32x4 bc = ntl4(xp + 2 * (size_t)HW);

    for (int it = 0; it < BATCH; ++it) {
        // issue next image's loads early (hidden under this image's compute)
        f32x4 rn = {}, gn = {}, bn = {};
        if (it != BATCH - 1) {
            const float* xn = xp + (size_t)(it + 1) * (3 * (size_t)HW);
            rn = ntl4(xn);
            gn = ntl4(xn + HW);
            bn = ntl4(xn + 2 * (size_t)HW);
        }

        // phase 1: indices + all 32 LDS gathers for the 4 pixels
        unsigned n[4][8];
        float fr[4], fg[4], fb[4];
#pragma unroll
        for (int i = 0; i < 4; ++i) {
            const float scale = (float)(DIM - 1);
            float rs = rc[i] * scale, gs = gc[i] * scale, bs = bc[i] * scale;
            int ir = (int)rs; ir = ir < 0 ? 0 : (ir > DIM - 2 ? DIM - 2 : ir);
            int ig = (int)gs; ig = ig < 0 ? 0 : (ig > DIM - 2 ? DIM - 2 : ig);
            int ib = (int)bs; ib = ib < 0 ? 0 : (ib > DIM - 2 ? DIM - 2 : ib);
            fr[i] = rs - (float)ir;
            fg[i] = gs - (float)ig;
            fb[i] = bs - (float)ib;
            int s = ib * (DIM * DIM) + ig * DIM + ir;
            n[i][0] = sl[s];                     n[i][1] = sl[s + 1];
            n[i][2] = sl[s + DIM];               n[i][3] = sl[s + DIM + 1];
            n[i][4] = sl[s + DIM * DIM];         n[i][5] = sl[s + DIM * DIM + 1];
            n[i][6] = sl[s + DIM * DIM + DIM];   n[i][7] = sl[s + DIM * DIM + DIM + 1];
        }

        // phase 2: decode + weighted sum (weights shared across 3 channels)
        f32x4 orv, ogv, obv;
#pragma unroll
        for (int i = 0; i < 4; ++i) {
            float frc = 1.0f - fr[i], fgc = 1.0f - fg[i], fbc = 1.0f - fb[i];
            float w00 = fbc * fgc, w01 = fbc * fg[i];
            float w10 = fb[i] * fgc, w11 = fb[i] * fg[i];
            float u0 = w00 * frc, u1 = w00 * fr[i];
            float u2 = w01 * frc, u3 = w01 * fr[i];
            float u4 = w10 * frc, u5 = w10 * fr[i];
            float u6 = w11 * frc, u7 = w11 * fr[i];

            float qr = u0 * d_r(n[i][0]);
            qr = fmaf(u1, d_r(n[i][1]), qr);
            qr = fmaf(u2, d_r(n[i][2]), qr);
            qr = fmaf(u3, d_r(n[i][3]), qr);
            qr = fmaf(u4, d_r(n[i][4]), qr);
            qr = fmaf(u5, d_r(n[i][5]), qr);
            qr = fmaf(u6, d_r(n[i][6]), qr);
            qr = fmaf(u7, d_r(n[i][7]), qr);

            float qg = u0 * d_g(n[i][0]);
            qg = fmaf(u1, d_g(n[i][1]), qg);
            qg = fmaf(u2, d_g(n[i][2]), qg);
            qg = fmaf(u3, d_g(n[i][3]), qg);
            qg = fmaf(u4, d_g(n[i][4]), qg);
            qg = fmaf(u5, d_g(n[i][5]), qg);
            qg = fmaf(u6, d_g(n[i][6]), qg);
            qg = fmaf(u7, d_g(n[i][7]), qg);

            float qb = u0 * d_b(n[i][0]);
            qb = fmaf(u1, d_b(n[i][1]), qb);
            qb = fmaf(u2, d_b(n[i][2]), qb);
            qb = fmaf(u3, d_b(n[i][3]), qb);
            qb = fmaf(u4, d_b(n[i][4]), qb);
            qb = fmaf(u5, d_b(n[i][5]), qb);
            qb = fmaf(u6, d_b(n[i][6]), qb);
            qb = fmaf(u7, d_b(n[i][7]), qb);

            orv[i] = fmaf(qr, inv, mn);
            ogv[i] = fmaf(qg, inv, mn);
            obv[i] = fmaf(qb, inv, mn);
        }

        float* o = op + (size_t)it * (3 * (size_t)HW);
        nts4(o, orv);
        nts4(o + HW, ogv);
        nts4(o + 2 * (size_t)HW, obv);

        rc = rn; gc = gn; bc = bn;
    }
}

// ---------------------------------------------------------------------------
// Fallback: direct SoA gathers, exact fp32 (kept as safety net; not used).
// ---------------------------------------------------------------------------
__global__ __launch_bounds__(256) void lut_apply_soa(
    const float* __restrict__ x, const float* __restrict__ lut,
    float* __restrict__ out) {
    long t = (long)blockIdx.x * 256 + threadIdx.x;
    long p = t * 4;
    int  b  = (int)(p >> 20);
    int  hw = (int)(p & (HW - 1));
    size_t base = (size_t)b * (3 * (size_t)HW) + (size_t)hw;

    float4 rv = *(const float4*)(x + base);
    float4 gv = *(const float4*)(x + base + (size_t)HW);
    float4 bv = *(const float4*)(x + base + 2 * (size_t)HW);

    float rr[4] = {rv.x, rv.y, rv.z, rv.w};
    float gg[4] = {gv.x, gv.y, gv.z, gv.w};
    float bb[4] = {bv.x, bv.y, bv.z, bv.w};
    float orr[4], org[4], orb[4];

#pragma unroll
    for (int i = 0; i < 4; ++i) {
        const float scale = (float)(DIM - 1);
        float rs = rr[i] * scale, gs = gg[i] * scale, bs = bb[i] * scale;
        int ir = (int)floorf(rs); ir = ir < 0 ? 0 : (ir > DIM - 2 ? DIM - 2 : ir);
        int ig = (int)floorf(gs); ig = ig < 0 ? 0 : (ig > DIM - 2 ? DIM - 2 : ig);
        int ib = (int)floorf(bs); ib = ib < 0 ? 0 : (ib > DIM - 2 ? DIM - 2 : ib);
        float fr = rs - (float)ir, fg = gs - (float)ig, fb = bs - (float)ib;
        int base_i = (ib * DIM + ig) * DIM + ir;
        float acc[3] = {0.f, 0.f, 0.f};
#pragma unroll
        for (int db = 0; db < 2; ++db) {
            float wb = db ? fb : 1.f - fb;
#pragma unroll
            for (int dg = 0; dg < 2; ++dg) {
                float wg = dg ? fg : 1.f - fg;
#pragma unroll
                for (int dr = 0; dr < 2; ++dr) {
                    float wr = dr ? fr : 1.f - fr;
                    int idx = base_i + (db * DIM + dg) * DIM + dr;
                    float w = wb * wg * wr;
                    acc[0] = fmaf(w, lut[idx], acc[0]);
                    acc[1] = fmaf(w, lut[LUT_N + idx], acc[1]);
                    acc[2] = fmaf(w, lut[2 * LUT_N + idx], acc[2]);
                }
            }
        }
        orr[i] = acc[0]; org[i] = acc[1]; orb[i] = acc[2];
    }

    *(float4*)(out + base)                  = make_float4(orr[0], orr[1], orr[2], orr[3]);
    *(float4*)(out + base + (size_t)HW)     = make_float4(org[0], org[1], org[2], org[3]);
    *(float4*)(out + base + 2 * (size_t)HW) = make_float4(orb[0], orb[1], orb[2], orb[3]);
}

extern "C" void kernel_launch(void* const* d_in, const int* in_sizes, int n_in,
                              void* d_out, int out_size, void* d_ws, size_t ws_size,
                              hipStream_t stream) {
    const float* lut = (const float*)d_in[0];
    const float* x   = (const float*)d_in[1];
    if (n_in >= 2 && in_sizes[0] > in_sizes[1]) {  // defensive: order swapped
        lut = (const float*)d_in[1];
        x   = (const float*)d_in[0];
    }
    float* out = (float*)d_out;
    (void)d_ws; (void)ws_size;

    // Allow >64KB dynamic LDS (gfx950 has 160 KiB). Host-side attr set,
    // idempotent, graph-capture safe.
    (void)hipFuncSetAttribute((const void*)lut_fused,
                              hipFuncAttributeMaxDynamicSharedMemorySize,
                              (int)LDS_BYTES);
    lut_fused<<<ABLK, ATHR, LDS_BYTES, stream>>>(x, lut, out);
}